// Round 2
// baseline (268.659 us; speedup 1.0000x reference)
//
#include <hip/hip_runtime.h>

#define NP 128

// Persistent grid-stride kernel with explicit 2-stage software pipeline.
// Wave layout: 64 lanes = 2 rays, 32 lanes/ray, 4 consecutive samples per lane
// (one float4 per stream). Each wave loops over ray-pairs with stride nwaves;
// while computing pair i (scan + reduce + stores), pair i+1's 6 float4 loads
// are already in flight. asm memory fences pin load-issue order against the
// compiler's min-register scheduling (which killed MLP in the previous rev).

struct Six {
    float4 den, dst, z, c0, c1, c2;
};

__device__ __forceinline__ void load6(const float* __restrict__ rgb,
                                      const float* __restrict__ density,
                                      const float* __restrict__ dists,
                                      const float* __restrict__ zvals,
                                      size_t base, size_t cstride, Six& r)
{
    r.den = *(const float4*)(density + base);
    r.dst = *(const float4*)(dists   + base);
    r.z   = *(const float4*)(zvals   + base);
    r.c0  = *(const float4*)(rgb + base);
    r.c1  = *(const float4*)(rgb + base + cstride);
    r.c2  = *(const float4*)(rgb + base + 2 * cstride);
}

__device__ __forceinline__ void compute(const Six& r, int ray, int sub, size_t base,
                                        float* __restrict__ out, int NR)
{
    const float a0 = 1.0f - __expf(-r.den.x * r.dst.x);
    const float a1 = 1.0f - __expf(-r.den.y * r.dst.y);
    const float a2 = 1.0f - __expf(-r.den.z * r.dst.z);
    const float a3 = 1.0f - __expf(-r.den.w * r.dst.w);
    const float x0 = 1.0f - a0 + 1e-10f;
    const float x1 = 1.0f - a1 + 1e-10f;
    const float x2 = 1.0f - a2 + 1e-10f;
    const float x3 = 1.0f - a3 + 1e-10f;

    const float p01  = x0 * x1;
    const float p012 = p01 * x2;
    float p = p01 * (x2 * x3);

    // inclusive prefix product across the 32-lane half-wave (5 dependent steps)
    #pragma unroll
    for (int off = 1; off < 32; off <<= 1) {
        const float v = __shfl_up(p, off, 32);
        if (sub >= off) p *= v;
    }
    float excl = __shfl_up(p, 1, 32);
    if (sub == 0) excl = 1.0f;

    const float w0 = a0 * excl;
    const float w1 = a1 * (excl * x0);
    const float w2 = a2 * (excl * p01);
    const float w3 = a3 * (excl * p012);

    *(float4*)(out + (size_t)5 * NR + base) = make_float4(w0, w1, w2, w3);

    float sdep = w0 * r.z.x + w1 * r.z.y + w2 * r.z.z + w3 * r.z.w;
    float sacc = (w0 + w1) + (w2 + w3);
    float s0   = w0 * r.c0.x + w1 * r.c0.y + w2 * r.c0.z + w3 * r.c0.w;
    float s1   = w0 * r.c1.x + w1 * r.c1.y + w2 * r.c1.z + w3 * r.c1.w;
    float s2   = w0 * r.c2.x + w1 * r.c2.y + w2 * r.c2.z + w3 * r.c2.w;

    // butterfly within each 32-lane half (xor off<32 never crosses halves)
    #pragma unroll
    for (int off = 16; off >= 1; off >>= 1) {
        s0   += __shfl_xor(s0, off);
        s1   += __shfl_xor(s1, off);
        s2   += __shfl_xor(s2, off);
        sdep += __shfl_xor(sdep, off);
        sacc += __shfl_xor(sacc, off);
    }

    if (sub == 0) {
        out[ray]                  = s0;
        out[(size_t)NR + ray]     = s1;
        out[2 * (size_t)NR + ray] = s2;
        out[3 * (size_t)NR + ray] = 1.0f - sacc;
        out[4 * (size_t)NR + ray] = sdep;
    }
}

__global__ __launch_bounds__(256) void calc_ray_color_kernel(
    const float* __restrict__ rgb,      // [3, NR, NP]
    const float* __restrict__ density,  // [NR, NP]
    const float* __restrict__ dists,    // [NR, NP]
    const float* __restrict__ zvals,    // [NR, NP]
    float* __restrict__ out,            // rgb_res[3*NR] | bg[NR] | depth[NR] | weight[NR*NP]
    int NR)
{
    const int tid  = threadIdx.x;
    const int sub  = tid & 31;                 // lane within the 32-lane ray group
    const int half = (tid >> 5) & 1;           // which ray of the wave's pair
    const int nwaves = (int)(gridDim.x << 2);  // 4 waves per 256-thread block
    const int npairs = (NR + 1) >> 1;
    const size_t cstride = (size_t)NR * NP;

    int pa = blockIdx.x * 4 + (tid >> 6);
    if (pa >= npairs) return;

    Six A, B;
    int rayA = 2 * pa + half;
    bool vA = rayA < NR;
    size_t baseA = (size_t)rayA * NP + 4 * sub;
    if (vA) load6(rgb, density, dists, zvals, baseA, cstride, A);

    for (;;) {
        // ---- stage: prefetch B, compute A ----
        const int pb = pa + nwaves;
        const int rayB = 2 * pb + half;
        const bool vB = (pb < npairs) && (rayB < NR);
        const size_t baseB = (size_t)rayB * NP + 4 * sub;
        if (vB) load6(rgb, density, dists, zvals, baseB, cstride, B);
        asm volatile("" ::: "memory");   // pin B's loads above A's compute
        if (vA) compute(A, rayA, sub, baseA, out, NR);
        if (pb >= npairs) return;

        // ---- stage: prefetch A, compute B ----
        pa = pb + nwaves;
        rayA = 2 * pa + half;
        vA = (pa < npairs) && (rayA < NR);
        baseA = (size_t)rayA * NP + 4 * sub;
        if (vA) load6(rgb, density, dists, zvals, baseA, cstride, A);
        asm volatile("" ::: "memory");   // pin A's loads above B's compute
        if (vB) compute(B, rayB, sub, baseB, out, NR);
        if (pa >= npairs) return;
    }
}

extern "C" void kernel_launch(void* const* d_in, const int* in_sizes, int n_in,
                              void* d_out, int out_size, void* d_ws, size_t ws_size,
                              hipStream_t stream) {
    // d_in[0] = fg_vps  (UNUSED by reference — do not read)
    const float* rgb     = (const float*)d_in[1];
    const float* density = (const float*)d_in[2];
    const float* dists   = (const float*)d_in[3];
    const float* zvals   = (const float*)d_in[4];
    float* out = (float*)d_out;

    const int NR = in_sizes[2] / NP;   // density is [1,1,NR,NP]
    const int npairs = (NR + 1) / 2;

    // Persistent-ish grid: cap at 2048 blocks (8 blocks/CU), grid-stride the rest.
    int blocks = (npairs + 3) / 4;     // 4 waves/block, 1 pair per wave-iteration
    if (blocks > 2048) blocks = 2048;

    calc_ray_color_kernel<<<blocks, 256, 0, stream>>>(rgb, density, dists, zvals, out, NR);
}

// Round 4
// 267.795 us; speedup vs baseline: 1.0032x; 1.0032x over previous
//
#include <hip/hip_runtime.h>

#define NP 128
#define WPB 4                  // waves per block (256 threads)
#define NSTREAM 6

// Counted wait + scheduler fence (rule #18: sched_barrier stops VALU/DS from
// hoisting above the waitcnt; "memory" clobber stops memory ops crossing it).
#define WAITV(n) do { asm volatile("s_waitcnt vmcnt(" #n ")" ::: "memory"); \
                      __builtin_amdgcn_sched_barrier(0); } while (0)

// Async global->LDS, 16B per lane. Dest is wave-uniform base + lane*16
// (linear layout = exactly our staging layout). Global source is per-lane.
__device__ __forceinline__ void gl_lds16(const float* g, float4* l) {
    __builtin_amdgcn_global_load_lds(
        (const __attribute__((address_space(1))) void*)g,
        (__attribute__((address_space(3))) void*)l,
        16, 0, 0);
}

__global__ __launch_bounds__(WPB * 64) void calc_ray_color_kernel(
    const float* __restrict__ rgb,      // [3, NR, NP]
    const float* __restrict__ density,  // [NR, NP]
    const float* __restrict__ dists,    // [NR, NP]
    const float* __restrict__ zvals,    // [NR, NP]
    float* __restrict__ out,            // rgb_res[3*NR] | bg[NR] | depth[NR] | weight[NR*NP]
    int NR)
{
    // Per-wave double buffer: [wave][buf][stream][lane] -> 48 KB/block.
    __shared__ float4 stage[WPB][2][NSTREAM][64];

    const int tid  = threadIdx.x;
    const int w    = tid >> 6;         // wave within block
    const int lane = tid & 63;
    const int sub  = lane & 31;        // lane within 32-lane ray group
    const int half = lane >> 5;        // which ray of the wave's pair
    const int nw   = (int)gridDim.x * WPB;
    const int npairs = (NR + 1) >> 1;
    const size_t cstride = (size_t)NR * NP;

    int p = (int)blockIdx.x * WPB + w;  // wave-uniform
    if (p >= npairs) return;

    // per-lane global element offset for pair pp (clamped: tail stays in-bounds)
    auto goff = [&](int pp) -> size_t {
        int ray = 2 * pp + half;
        if (ray > NR - 1) ray = NR - 1;
        return (size_t)ray * NP + 4 * sub;
    };

    auto issue = [&](int pp, int buf) {
        const size_t b = goff(pp);
        gl_lds16(density + b,            &stage[w][buf][0][0]);
        gl_lds16(dists   + b,            &stage[w][buf][1][0]);
        gl_lds16(zvals   + b,            &stage[w][buf][2][0]);
        gl_lds16(rgb + b,                &stage[w][buf][3][0]);
        gl_lds16(rgb + b + cstride,      &stage[w][buf][4][0]);
        gl_lds16(rgb + b + 2 * cstride,  &stage[w][buf][5][0]);
    };

    issue(p, 0);                       // prologue: fill buffer 0
    int cur = 0;

    for (;;) {
        const int pn   = p + nw;
        const bool have = pn < npairs;  // wave-uniform
        if (have) {
            issue(pn, cur ^ 1);        // next pair's loads go in flight...
            WAITV(6);                  // ...and are the ONLY 6 allowed to remain:
                                       // current buffer + all older stores drained.
        } else {
            WAITV(0);
        }

        // ---- consume current buffer (ds_read_b128, conflict-free linear) ----
        const float4 den = stage[w][cur][0][lane];
        const float4 dst = stage[w][cur][1][lane];
        const float4 z   = stage[w][cur][2][lane];
        const float4 c0  = stage[w][cur][3][lane];
        const float4 c1  = stage[w][cur][4][lane];
        const float4 c2  = stage[w][cur][5][lane];

        const int  ray  = 2 * p + half;
        const bool vray = ray < NR;
        const size_t base = (size_t)(vray ? ray : 0) * NP + 4 * sub;

        const float a0 = 1.0f - __expf(-den.x * dst.x);
        const float a1 = 1.0f - __expf(-den.y * dst.y);
        const float a2 = 1.0f - __expf(-den.z * dst.z);
        const float a3 = 1.0f - __expf(-den.w * dst.w);
        const float x0 = 1.0f - a0 + 1e-10f;
        const float x1 = 1.0f - a1 + 1e-10f;
        const float x2 = 1.0f - a2 + 1e-10f;
        const float x3 = 1.0f - a3 + 1e-10f;

        const float p01  = x0 * x1;
        const float p012 = p01 * x2;
        float pr = p01 * (x2 * x3);

        // inclusive prefix product across the 32-lane half-wave
        #pragma unroll
        for (int off = 1; off < 32; off <<= 1) {
            const float v = __shfl_up(pr, off, 32);
            if (sub >= off) pr *= v;
        }
        float excl = __shfl_up(pr, 1, 32);
        if (sub == 0) excl = 1.0f;

        const float w0 = a0 * excl;
        const float w1 = a1 * (excl * x0);
        const float w2 = a2 * (excl * p01);
        const float w3 = a3 * (excl * p012);

        if (vray)
            *(float4*)(out + (size_t)5 * NR + base) = make_float4(w0, w1, w2, w3);

        float sdep = w0 * z.x + w1 * z.y + w2 * z.z + w3 * z.w;
        float sacc = (w0 + w1) + (w2 + w3);
        float s0   = w0 * c0.x + w1 * c0.y + w2 * c0.z + w3 * c0.w;
        float s1   = w0 * c1.x + w1 * c1.y + w2 * c1.z + w3 * c1.w;
        float s2   = w0 * c2.x + w1 * c2.y + w2 * c2.z + w3 * c2.w;

        // butterfly within each 32-lane half (xor off<32 never crosses halves)
        #pragma unroll
        for (int off = 16; off >= 1; off >>= 1) {
            s0   += __shfl_xor(s0, off);
            s1   += __shfl_xor(s1, off);
            s2   += __shfl_xor(s2, off);
            sdep += __shfl_xor(sdep, off);
            sacc += __shfl_xor(sacc, off);
        }

        if (sub == 0 && vray) {
            out[ray]                  = s0;
            out[(size_t)NR + ray]     = s1;
            out[2 * (size_t)NR + ray] = s2;
            out[3 * (size_t)NR + ray] = 1.0f - sacc;
            out[4 * (size_t)NR + ray] = sdep;
        }

        if (!have) return;
        p = pn;
        cur ^= 1;
    }
}

extern "C" void kernel_launch(void* const* d_in, const int* in_sizes, int n_in,
                              void* d_out, int out_size, void* d_ws, size_t ws_size,
                              hipStream_t stream) {
    // d_in[0] = fg_vps  (UNUSED by reference — do not read)
    const float* rgb     = (const float*)d_in[1];
    const float* density = (const float*)d_in[2];
    const float* dists   = (const float*)d_in[3];
    const float* zvals   = (const float*)d_in[4];
    float* out = (float*)d_out;

    const int NR = in_sizes[2] / NP;   // density is [1,1,NR,NP]
    const int npairs = (NR + 1) / 2;

    // 48 KB LDS/block -> 3 blocks/CU resident; 768 blocks = one resident set,
    // each wave pipelines ~npairs/3072 pairs back-to-back.
    int blocks = (npairs + WPB - 1) / WPB;
    if (blocks > 768) blocks = 768;

    calc_ray_color_kernel<<<blocks, WPB * 64, 0, stream>>>(rgb, density, dists, zvals, out, NR);
}

// Round 6
// 264.604 us; speedup vs baseline: 1.0153x; 1.0121x over previous
//
#include <hip/hip_runtime.h>

#define NP 128

// Round-0 structure (best measured: 81.0 us/dispatch) + non-temporal stores.
// One wave (64 lanes) per ray; lane i owns samples 2i, 2i+1 (float2, fully
// coalesced). Exclusive cumprod = per-lane pair product + 6-step shfl_up scan.
// All outputs stored non-temporally: the 34 MB/dispatch of write traffic is
// never re-read by anyone, and normal stores were evicting ~34 MB of the
// input set from the 256 MiB L3 (working set 235 MB = right at capacity).
// NOTE: __builtin_nontemporal_store needs clang-native vector types, not
// HIP_vector_type structs -> use ext_vector_type(2) for the paired store.
typedef float vfloat2 __attribute__((ext_vector_type(2)));

__global__ __launch_bounds__(256) void calc_ray_color_kernel(
    const float* __restrict__ rgb,      // [3, NR, NP]
    const float* __restrict__ density,  // [NR, NP]
    const float* __restrict__ dists,    // [NR, NP]
    const float* __restrict__ zvals,    // [NR, NP]
    float* __restrict__ out,            // rgb_res[3*NR] | bg[NR] | depth[NR] | weight[NR*NP]
    int NR)
{
    const int lane = threadIdx.x & 63;
    const int ray  = (blockIdx.x << 2) + (threadIdx.x >> 6);
    if (ray >= NR) return;

    const size_t base = (size_t)ray * NP + 2 * lane;

    float2 den = *(const float2*)(density + base);
    float2 dst = *(const float2*)(dists + base);

    float a0 = 1.0f - __expf(-den.x * dst.x);
    float a1 = 1.0f - __expf(-den.y * dst.y);
    float x0 = 1.0f - a0 + 1e-10f;
    float x1 = 1.0f - a1 + 1e-10f;

    // inclusive prefix product of per-lane pair products across the wave
    float p = x0 * x1;
    #pragma unroll
    for (int off = 1; off < 64; off <<= 1) {
        float v = __shfl_up(p, off);
        if (lane >= off) p *= v;
    }
    // exclusive
    float excl = __shfl_up(p, 1);
    if (lane == 0) excl = 1.0f;

    const float t0 = excl;
    const float t1 = excl * x0;
    const float w0 = a0 * t0;
    const float w1 = a1 * t1;

    // weight out (after the 5*NR scalar outputs) — non-temporal, write-only data
    {
        vfloat2 wv;
        wv.x = w0;
        wv.y = w1;
        __builtin_nontemporal_store(wv, (vfloat2*)(out + (size_t)5 * NR + base));
    }

    float2 z = *(const float2*)(zvals + base);
    float sdep = w0 * z.x + w1 * z.y;
    float sacc = w0 + w1;

    const float* rgb_ray = rgb + base;
    const size_t cstride = (size_t)NR * NP;
    float2 c0 = *(const float2*)(rgb_ray);
    float2 c1 = *(const float2*)(rgb_ray + cstride);
    float2 c2 = *(const float2*)(rgb_ray + 2 * cstride);
    float s0 = w0 * c0.x + w1 * c0.y;
    float s1 = w0 * c1.x + w1 * c1.y;
    float s2 = w0 * c2.x + w1 * c2.y;

    // wave reductions
    #pragma unroll
    for (int off = 32; off >= 1; off >>= 1) {
        s0   += __shfl_down(s0, off);
        s1   += __shfl_down(s1, off);
        s2   += __shfl_down(s2, off);
        sdep += __shfl_down(sdep, off);
        sacc += __shfl_down(sacc, off);
    }

    if (lane == 0) {
        __builtin_nontemporal_store(s0,          out + ray);
        __builtin_nontemporal_store(s1,          out + (size_t)NR + ray);
        __builtin_nontemporal_store(s2,          out + 2 * (size_t)NR + ray);
        __builtin_nontemporal_store(1.0f - sacc, out + 3 * (size_t)NR + ray);
        __builtin_nontemporal_store(sdep,        out + 4 * (size_t)NR + ray);
    }
}

extern "C" void kernel_launch(void* const* d_in, const int* in_sizes, int n_in,
                              void* d_out, int out_size, void* d_ws, size_t ws_size,
                              hipStream_t stream) {
    // d_in[0] = fg_vps  (UNUSED by reference — do not read)
    const float* rgb     = (const float*)d_in[1];
    const float* density = (const float*)d_in[2];
    const float* dists   = (const float*)d_in[3];
    const float* zvals   = (const float*)d_in[4];
    float* out = (float*)d_out;

    const int NR = in_sizes[2] / NP;   // density is [1,1,NR,NP]
    const int rays_per_block = 4;      // 256 threads = 4 waves
    const int grid = (NR + rays_per_block - 1) / rays_per_block;

    calc_ray_color_kernel<<<grid, 256, 0, stream>>>(rgb, density, dists, zvals, out, NR);
}

// Round 7
// 252.270 us; speedup vs baseline: 1.0650x; 1.0489x over previous
//
#include <hip/hip_runtime.h>

#define NP 128

// Round-0 structure (best measured: 81.0 us/dispatch) + NON-TEMPORAL LOADS.
// Experiment: bypass L2/L3 allocation on all 6 input streams (nt bit). Today
// ~50% of reads are L3 hits yet aggregate service sits at 2.9 TB/s with no
// pipe >21% busy across six structural variants. If the mixed L3-hit/miss
// allocation path is the serializer, straight-to-HBM reads re-regime the
// kernel (236 MB @ 6.3 TB/s ~ 37 us). NT stores kept from round 6 (neutral).
typedef float vfloat2 __attribute__((ext_vector_type(2)));

__device__ __forceinline__ vfloat2 ntload2(const float* p) {
    return __builtin_nontemporal_load((const vfloat2*)p);
}

__global__ __launch_bounds__(256) void calc_ray_color_kernel(
    const float* __restrict__ rgb,      // [3, NR, NP]
    const float* __restrict__ density,  // [NR, NP]
    const float* __restrict__ dists,    // [NR, NP]
    const float* __restrict__ zvals,    // [NR, NP]
    float* __restrict__ out,            // rgb_res[3*NR] | bg[NR] | depth[NR] | weight[NR*NP]
    int NR)
{
    const int lane = threadIdx.x & 63;
    const int ray  = (blockIdx.x << 2) + (threadIdx.x >> 6);
    if (ray >= NR) return;

    const size_t base = (size_t)ray * NP + 2 * lane;

    const vfloat2 den = ntload2(density + base);
    const vfloat2 dst = ntload2(dists + base);

    float a0 = 1.0f - __expf(-den.x * dst.x);
    float a1 = 1.0f - __expf(-den.y * dst.y);
    float x0 = 1.0f - a0 + 1e-10f;
    float x1 = 1.0f - a1 + 1e-10f;

    // inclusive prefix product of per-lane pair products across the wave
    float p = x0 * x1;
    #pragma unroll
    for (int off = 1; off < 64; off <<= 1) {
        float v = __shfl_up(p, off);
        if (lane >= off) p *= v;
    }
    // exclusive
    float excl = __shfl_up(p, 1);
    if (lane == 0) excl = 1.0f;

    const float t0 = excl;
    const float t1 = excl * x0;
    const float w0 = a0 * t0;
    const float w1 = a1 * t1;

    // weight out (after the 5*NR scalar outputs) — non-temporal, write-only data
    {
        vfloat2 wv;
        wv.x = w0;
        wv.y = w1;
        __builtin_nontemporal_store(wv, (vfloat2*)(out + (size_t)5 * NR + base));
    }

    const vfloat2 z = ntload2(zvals + base);
    float sdep = w0 * z.x + w1 * z.y;
    float sacc = w0 + w1;

    const float* rgb_ray = rgb + base;
    const size_t cstride = (size_t)NR * NP;
    const vfloat2 c0 = ntload2(rgb_ray);
    const vfloat2 c1 = ntload2(rgb_ray + cstride);
    const vfloat2 c2 = ntload2(rgb_ray + 2 * cstride);
    float s0 = w0 * c0.x + w1 * c0.y;
    float s1 = w0 * c1.x + w1 * c1.y;
    float s2 = w0 * c2.x + w1 * c2.y;

    // wave reductions
    #pragma unroll
    for (int off = 32; off >= 1; off >>= 1) {
        s0   += __shfl_down(s0, off);
        s1   += __shfl_down(s1, off);
        s2   += __shfl_down(s2, off);
        sdep += __shfl_down(sdep, off);
        sacc += __shfl_down(sacc, off);
    }

    if (lane == 0) {
        __builtin_nontemporal_store(s0,          out + ray);
        __builtin_nontemporal_store(s1,          out + (size_t)NR + ray);
        __builtin_nontemporal_store(s2,          out + 2 * (size_t)NR + ray);
        __builtin_nontemporal_store(1.0f - sacc, out + 3 * (size_t)NR + ray);
        __builtin_nontemporal_store(sdep,        out + 4 * (size_t)NR + ray);
    }
}

extern "C" void kernel_launch(void* const* d_in, const int* in_sizes, int n_in,
                              void* d_out, int out_size, void* d_ws, size_t ws_size,
                              hipStream_t stream) {
    // d_in[0] = fg_vps  (UNUSED by reference — do not read)
    const float* rgb     = (const float*)d_in[1];
    const float* density = (const float*)d_in[2];
    const float* dists   = (const float*)d_in[3];
    const float* zvals   = (const float*)d_in[4];
    float* out = (float*)d_out;

    const int NR = in_sizes[2] / NP;   // density is [1,1,NR,NP]
    const int rays_per_block = 4;      // 256 threads = 4 waves
    const int grid = (NR + rays_per_block - 1) / rays_per_block;

    calc_ray_color_kernel<<<grid, 256, 0, stream>>>(rgb, density, dists, zvals, out, NR);
}

// Round 8
// 251.165 us; speedup vs baseline: 1.0696x; 1.0044x over previous
//
#include <hip/hip_runtime.h>

#define NP 128

// NT-load/store streaming kernel (round-7 win: bypassing L2/L3 allocation
// broke the 2.9 TB/s cache-path wall; kernel 81 -> <58 us) + float4 width.
// 2 rays per wave: lanes [0..31] own ray r0, lanes [32..63] own ray r1.
// Each lane holds 4 consecutive samples (one 16B NT load per stream):
// half the vmem instructions and waves of the float2 version, 2x bytes in
// flight per wave — now that we're in the HBM-streaming regime, request
// width is what closes the gap to the ~6.9 TB/s ceiling.
typedef float vfloat4 __attribute__((ext_vector_type(4)));

__device__ __forceinline__ vfloat4 ntload4(const float* p) {
    return __builtin_nontemporal_load((const vfloat4*)p);
}

__global__ __launch_bounds__(256) void calc_ray_color_kernel(
    const float* __restrict__ rgb,      // [3, NR, NP]
    const float* __restrict__ density,  // [NR, NP]
    const float* __restrict__ dists,    // [NR, NP]
    const float* __restrict__ zvals,    // [NR, NP]
    float* __restrict__ out,            // rgb_res[3*NR] | bg[NR] | depth[NR] | weight[NR*NP]
    int NR)
{
    const int tid = threadIdx.x;
    const int sub = tid & 31;                      // lane within the 32-lane ray group
    const int ray = blockIdx.x * 8 + (tid >> 5);   // 8 rays per 256-thread block
    if (ray >= NR) return;

    const size_t base    = (size_t)ray * NP + 4 * sub;
    const size_t cstride = (size_t)NR * NP;

    const vfloat4 den = ntload4(density + base);
    const vfloat4 dst = ntload4(dists   + base);
    const vfloat4 z   = ntload4(zvals   + base);
    const vfloat4 c0  = ntload4(rgb + base);
    const vfloat4 c1  = ntload4(rgb + base + cstride);
    const vfloat4 c2  = ntload4(rgb + base + 2 * cstride);

    const float a0 = 1.0f - __expf(-den.x * dst.x);
    const float a1 = 1.0f - __expf(-den.y * dst.y);
    const float a2 = 1.0f - __expf(-den.z * dst.z);
    const float a3 = 1.0f - __expf(-den.w * dst.w);
    const float x0 = 1.0f - a0 + 1e-10f;
    const float x1 = 1.0f - a1 + 1e-10f;
    const float x2 = 1.0f - a2 + 1e-10f;
    const float x3 = 1.0f - a3 + 1e-10f;

    const float p01  = x0 * x1;
    const float p012 = p01 * x2;
    float p = p01 * (x2 * x3);

    // inclusive prefix product across the 32-lane group (5 dependent steps)
    #pragma unroll
    for (int off = 1; off < 32; off <<= 1) {
        const float v = __shfl_up(p, off, 32);
        if (sub >= off) p *= v;
    }
    float excl = __shfl_up(p, 1, 32);
    if (sub == 0) excl = 1.0f;

    const float w0 = a0 * excl;
    const float w1 = a1 * (excl * x0);
    const float w2 = a2 * (excl * p01);
    const float w3 = a3 * (excl * p012);

    // weight output — non-temporal 16B store
    {
        vfloat4 wv;
        wv.x = w0; wv.y = w1; wv.z = w2; wv.w = w3;
        __builtin_nontemporal_store(wv, (vfloat4*)(out + (size_t)5 * NR + base));
    }

    float sdep = w0 * z.x + w1 * z.y + w2 * z.z + w3 * z.w;
    float sacc = (w0 + w1) + (w2 + w3);
    float s0   = w0 * c0.x + w1 * c0.y + w2 * c0.z + w3 * c0.w;
    float s1   = w0 * c1.x + w1 * c1.y + w2 * c1.z + w3 * c1.w;
    float s2   = w0 * c2.x + w1 * c2.y + w2 * c2.z + w3 * c2.w;

    // butterfly reduce within each 32-lane group (xor off<32 stays in-group)
    #pragma unroll
    for (int off = 16; off >= 1; off >>= 1) {
        s0   += __shfl_xor(s0, off);
        s1   += __shfl_xor(s1, off);
        s2   += __shfl_xor(s2, off);
        sdep += __shfl_xor(sdep, off);
        sacc += __shfl_xor(sacc, off);
    }

    if (sub == 0) {
        __builtin_nontemporal_store(s0,          out + ray);
        __builtin_nontemporal_store(s1,          out + (size_t)NR + ray);
        __builtin_nontemporal_store(s2,          out + 2 * (size_t)NR + ray);
        __builtin_nontemporal_store(1.0f - sacc, out + 3 * (size_t)NR + ray);
        __builtin_nontemporal_store(sdep,        out + 4 * (size_t)NR + ray);
    }
}

extern "C" void kernel_launch(void* const* d_in, const int* in_sizes, int n_in,
                              void* d_out, int out_size, void* d_ws, size_t ws_size,
                              hipStream_t stream) {
    // d_in[0] = fg_vps  (UNUSED by reference — do not read)
    const float* rgb     = (const float*)d_in[1];
    const float* density = (const float*)d_in[2];
    const float* dists   = (const float*)d_in[3];
    const float* zvals   = (const float*)d_in[4];
    float* out = (float*)d_out;

    const int NR = in_sizes[2] / NP;   // density is [1,1,NR,NP]
    const int rays_per_block = 8;      // 256 threads = 8 ray-groups of 32 lanes
    const int grid = (NR + rays_per_block - 1) / rays_per_block;

    calc_ray_color_kernel<<<grid, 256, 0, stream>>>(rgb, density, dists, zvals, out, NR);
}